// Round 16
// baseline (213.039 us; speedup 1.0000x reference)
//
#include <hip/hip_runtime.h>
#include <stdint.h>

#define TSTEPS 256
#define NB 16
#define NM (TSTEPS*NB)   // 4096

typedef short s16x2 __attribute__((ext_vector_type(2)));

// perm(i) = bitrev8(gray(i)) : the Sobol value rng[i] = 2*perm8(i)/256 - 1
__device__ __forceinline__ uint32_t perm8(int i) {
  uint32_t g = (uint32_t)(i ^ (i >> 1));
  return __brev(g) >> 24;
}

// z = a*t + e (packed i16), t wave-uniform in SGPR
__device__ __forceinline__ void qmad(uint32_t& z, uint32_t a, uint32_t t_s,
                                     uint32_t e) {
  asm("v_pk_mad_i16 %0, %1, %2, %3" : "=v"(z) : "v"(a), "s"(t_s), "v"(e));
}
__device__ __forceinline__ uint32_t qperm(uint32_t x, uint32_t y, uint32_t sel) {
  uint32_t d;
  asm("v_perm_b32 %0, %1, %2, %3" : "=v"(d) : "v"(x), "v"(y), "v"(sel));
  return d;
}
// acc += byte0+byte1+byte2+byte3 of p  (each byte is 0x00 or 0xFF exactly)
__device__ __forceinline__ void qsad(uint32_t& acc, uint32_t p) {
  asm("v_sad_u8 %0, %1, 0, %0" : "+v"(acc) : "v"(p));
}

// all-VGPR compare step (l3 only)
__device__ __forceinline__ void qstep3(uint32_t& acc, uint32_t t2, uint32_t a2,
                                       uint32_t e2, uint32_t c15) {
  uint32_t z;
  asm("v_pk_mad_i16 %0, %2, %3, %4\n\t"
      "v_pk_ashrrev_i16 %0, %5, %0\n\t"
      "v_pk_add_i16 %1, %1, %0"
      : "=&v"(z), "+v"(acc)
      : "v"(a2), "v"(t2), "v"(e2), "v"(c15));
}

__device__ __forceinline__ uint32_t pkadd16(uint32_t a, uint32_t b) {
  return __builtin_bit_cast(uint32_t,
        (s16x2)(__builtin_bit_cast(s16x2, a) + __builtin_bit_cast(s16x2, b)));
}

// unpack packed v16 (u | xbar<<15) pair -> (a2, e2)
__device__ __forceinline__ void unpackAE(uint32_t v2, uint32_t& a2, uint32_t& e2) {
  s16x2 sv = __builtin_bit_cast(s16x2, v2) >> 15;      // 0 / -1 per half (xbar)
  uint32_t su = __builtin_bit_cast(uint32_t, sv);
  uint32_t vand = v2 & 0x01FF01FFu;
  e2 = pkadd16(~vand, su & 0x01FF01FFu);
  a2 = pkadd16(0x00010001u, pkadd16(su, su));          // +1 / -1
}

__device__ __forceinline__ int rank256(float w) {
  double v = 128.0 * (double)w + 128.0;
  int t = (int)ceil(v);
  if (t < 0) t = 0; if (t > 256) t = 256;
  return t;
}

#define SUMLOHI(A,B,C,D, LO, HI) \
  LO = (A & 0xFFFFu) + (B & 0xFFFFu) + (C & 0xFFFFu) + (D & 0xFFFFu); \
  HI = (A >> 16) + (B >> 16) + (C >> 16) + (D >> 16);

// ----------------- fused prep: rank tables + bias bitmasks + x chunk sums
// T1/T2 CHUNK-INTERLEAVED layout: Tc[(kp>>2)*NT + n]*4 + (kp&3).
__global__ __launch_bounds__(256) void k_prepA(
    const float* __restrict__ w1, const float* __restrict__ w2,
    const float* __restrict__ w3, const float* __restrict__ b1,
    const float* __restrict__ b2, const float* __restrict__ b3,
    const int* __restrict__ x,
    uint32_t* __restrict__ T1, uint32_t* __restrict__ T2,
    uint32_t* __restrict__ T3t, uint32_t* __restrict__ bb1,
    uint32_t* __restrict__ bb2, uint32_t* __restrict__ bb3,
    uint16_t* __restrict__ cs)
{
  int bid = blockIdx.x, tid = threadIdx.x;
  if (bid < 1024) {                      // w1 -> T1c chunk layout (512 n, 512 kp)
    int e = bid * 256 + tid;             // e = n*512 + kp
    int n = e >> 9, kp = e & 511;
    int dst = ((kp >> 2) * 512 + n) * 4 + (kp & 3);
    T1[dst] = (uint32_t)rank256(w1[2 * e]) |
              ((uint32_t)rank256(w1[2 * e + 1]) << 16);
  } else if (bid < 1280) {               // w2 -> T2c chunk layout (256 n, 256 kp)
    int e = (bid - 1024) * 256 + tid;    // e = n*256 + kp
    int n = e >> 8, kp = e & 255;
    int dst = ((kp >> 2) * 256 + n) * 4 + (kp & 3);
    T2[dst] = (uint32_t)rank256(w2[2 * e]) |
              ((uint32_t)rank256(w2[2 * e + 1]) << 16);
  } else if (bid < 1285) {               // w3 -> T3t [128 kp][10 n]
    int e = (bid - 1280) * 256 + tid;
    if (e < 1280) {
      int n = e % 10, kp = e / 10;
      T3t[e] = (uint32_t)rank256(w3[n * 256 + 2 * kp]) |
               ((uint32_t)rank256(w3[n * 256 + 2 * kp + 1]) << 16);
    }
  } else if (bid < 1301) {               // bb1: 512 o x 8 words
    int w = (bid - 1285) * 256 + tid;
    int o = w >> 3, j = w & 7;
    double bv = (double)b1[o] * 128.0 + 128.0;
    uint32_t bits = 0;
    for (int s = 0; s < 32; ++s)
      if (bv > (double)perm8(j * 32 + s)) bits |= 1u << s;
    bb1[w] = bits;
  } else if (bid < 1309) {               // bb2: 256 o x 8 words
    int w = (bid - 1301) * 256 + tid;
    int o = w >> 3, j = w & 7;
    double bv = (double)b2[o] * 128.0 + 128.0;
    uint32_t bits = 0;
    for (int s = 0; s < 32; ++s)
      if (bv > (double)perm8(j * 32 + s)) bits |= 1u << s;
    bb2[w] = bits;
  } else if (bid == 1309) {              // bb3: 10 o x 8 words
    if (tid < 80) {
      int o = tid >> 3, j = tid & 7;
      double bv = (double)b3[o] * 128.0 + 128.0;
      uint32_t bits = 0;
      for (int s = 0; s < 32; ++s)
        if (bv > (double)perm8(j * 32 + s)) bits |= 1u << s;
      bb3[tid] = bits;
    }
  } else {                               // x chunk sums (512 blocks)
    int g = (bid - 1310) * 256 + tid;
    int i = g & 1023, b = (g >> 10) & 15, c = g >> 14;
    int s = 0, t0 = c * 32;
    for (int tt = t0; tt < t0 + 32; ++tt)
      s += x[((size_t)tt * NB + b) * 1024 + i];
    cs[(c * NB + b) * 1024 + i] = (uint16_t)s;
  }
}

// ------------- layer-1 AE build (m = b*256+t): each thread owns an i-PAIR,
// builds the packed v-words for both halves and stores (a2,e2) directly via
// the SAME unpackAE bit path the GEMM used (no re-derivation).
__global__ __launch_bounds__(256) void k_prep1ae(const int* __restrict__ x,
                                                 const uint16_t* __restrict__ cs,
                                                 uint2* __restrict__ AE1) {
  int g = blockIdx.x * 256 + threadIdx.x;       // 65536
  int ip = g & 511;                             // i-pair
  int b = (g >> 9) & 15, c = g >> 13;           // c in 0..7
  int i0 = 2 * ip;
  int cum0 = 0, cum1 = 0;
  for (int cc = 0; cc < c; ++cc) {
    uint32_t two = *(const uint32_t*)(cs + (cc * NB + b) * 1024 + i0);
    cum0 += (int)(two & 0xFFFFu);
    cum1 += (int)(two >> 16);
  }
  int t0 = c * 32;
  for (int tt = t0; tt < t0 + 32; ++tt) {
    int m = b * 256 + tt;
    int2 xv = *(const int2*)(x + ((size_t)tt * NB + b) * 1024 + i0);
    int idx0 = xv.x ? cum0 : (tt - cum0);
    int idx1 = xv.y ? cum1 : (tt - cum1);
    uint32_t p0 = perm8(idx0), p1 = perm8(idx1);
    uint32_t v0 = (xv.x ? p0 : (510u - p0)) | ((uint32_t)(xv.x ^ 1) << 15);
    uint32_t v1 = (xv.y ? p1 : (510u - p1)) | ((uint32_t)(xv.y ^ 1) << 15);
    uint32_t a2, e2;
    unpackAE(v0 | (v1 << 16), a2, e2);
    AE1[(size_t)m * 512 + ip] = make_uint2(a2, e2);
    cum0 += xv.x; cum1 += xv.y;
  }
}

// ---------------- perm+SAD binary GEMM, interleaved-AE operand (layer 1).
// unroll 1 + fence (proven resident shape, R13). NEW: AE software prefetch —
// next chunk's two uint4 loads issue before the current chunk's compute, so
// the per-iteration serial VMEM latency is overlapped.
template<int KD, int NT, int NREG, int KC>
__global__ __launch_bounds__(256, 4) void k_gemmv6(
    const uint2* __restrict__ AE, const uint32_t* __restrict__ T,
    uint16_t* __restrict__ Yp)
{
  const int tid = threadIdx.x;
  const int m = blockIdx.x * 256 + tid;
  const int n0 = blockIdx.y * NREG;
  const int sk = blockIdx.z;
  const int k0 = sk * KC;
  uint32_t sel = 0x07050301u;
  uint32_t acc[NREG];
  #pragma unroll
  for (int nn = 0; nn < NREG; ++nn) acc[nn] = 0;
  const uint4* vsrc = (const uint4*)(AE + (size_t)m * (KD / 2) + (k0 >> 1));
  const uint32_t* tcbase = T + ((size_t)(k0 >> 3) * NT + n0) * 4;
  uint4 w01 = vsrc[0];
  uint4 w23 = vsrc[1];
  #pragma unroll 1
  for (int c = 0; c < KC / 8; ++c) {
    int cn = (c + 1 < KC / 8) ? c + 1 : c;          // clamped prefetch
    uint4 nx01 = vsrc[2 * cn];
    uint4 nx23 = vsrc[2 * cn + 1];
    uint32_t a0 = w01.x, e0 = w01.y, a1 = w01.z, e1 = w01.w;
    uint32_t a2v = w23.x, e2v = w23.y, a3 = w23.z, e3 = w23.w;
    // pin: one use per chunk, shared by all NREG chains (R9/R10 lesson)
    asm volatile("" : "+v"(a0), "+v"(e0), "+v"(a1), "+v"(e1),
                      "+v"(a2v), "+v"(e2v), "+v"(a3), "+v"(e3));
    const uint4* tcp = (const uint4*)(tcbase + (size_t)c * NT * 4);
    uint4 tw[NREG];
    #pragma unroll
    for (int nn = 0; nn < NREG; ++nn) tw[nn] = tcp[nn];  // contiguous SMEM
    #pragma unroll
    for (int nn = 0; nn < NREG; ++nn) {
      uint32_t z0, z1, z2, z3;
      qmad(z0, a0, tw[nn].x, e0);
      qmad(z1, a1, tw[nn].y, e1);
      qmad(z2, a2v, tw[nn].z, e2v);
      qmad(z3, a3, tw[nn].w, e3);
      qsad(acc[nn], qperm(z0, z1, sel));
      qsad(acc[nn], qperm(z2, z3, sel));
    }
    w01 = nx01; w23 = nx23;
  }
  uint16_t* outp = Yp + ((size_t)sk * NT + n0) * (size_t)NM + m;
  #pragma unroll
  for (int nn = 0; nn < NREG; ++nn)
    outp[(size_t)nn * NM] = (uint16_t)acc[nn];
}

// ---------------- perm+SAD binary GEMM, split A/E planes (layer 2) — no
// unpack. Chunk-layout T, unroll 1, AE prefetch.
template<int KD, int NT, int NREG, int KC>
__global__ __launch_bounds__(256, 4) void k_gemmv6b(
    const uint16_t* __restrict__ A, const uint16_t* __restrict__ E,
    const uint32_t* __restrict__ T, uint16_t* __restrict__ Yp)
{
  const int tid = threadIdx.x;
  const int m = blockIdx.x * 256 + tid;
  const int n0 = blockIdx.y * NREG;
  const int sk = blockIdx.z;
  const int k0 = sk * KC;
  uint32_t sel = 0x07050301u;
  uint32_t acc[NREG];
  #pragma unroll
  for (int nn = 0; nn < NREG; ++nn) acc[nn] = 0;
  const uint4* asrc = (const uint4*)(A + (size_t)m * KD + k0);
  const uint4* esrc = (const uint4*)(E + (size_t)m * KD + k0);
  const uint32_t* tcbase = T + ((size_t)(k0 >> 3) * NT + n0) * 4;
  uint4 aw = asrc[0];
  uint4 ew = esrc[0];
  #pragma unroll 1
  for (int c = 0; c < KC / 8; ++c) {
    int cn = (c + 1 < KC / 8) ? c + 1 : c;
    uint4 nxa = asrc[cn];
    uint4 nxe = esrc[cn];
    uint32_t a0 = aw.x, a1 = aw.y, a2v = aw.z, a3 = aw.w;
    uint32_t e0 = ew.x, e1 = ew.y, e2v = ew.z, e3 = ew.w;
    asm volatile("" : "+v"(a0), "+v"(e0), "+v"(a1), "+v"(e1),
                      "+v"(a2v), "+v"(e2v), "+v"(a3), "+v"(e3));
    const uint4* tcp = (const uint4*)(tcbase + (size_t)c * NT * 4);
    uint4 tw[NREG];
    #pragma unroll
    for (int nn = 0; nn < NREG; ++nn) tw[nn] = tcp[nn];
    #pragma unroll
    for (int nn = 0; nn < NREG; ++nn) {
      uint32_t z0, z1, z2, z3;
      qmad(z0, a0, tw[nn].x, e0);
      qmad(z1, a1, tw[nn].y, e1);
      qmad(z2, a2v, tw[nn].z, e2v);
      qmad(z3, a3, tw[nn].w, e3);
      qsad(acc[nn], qperm(z0, z1, sel));
      qsad(acc[nn], qperm(z2, z3, sel));
    }
    aw = nxa; ew = nxe;
  }
  uint16_t* outp = Yp + ((size_t)sk * NT + n0) * (size_t)NM + m;
  #pragma unroll
  for (int nn = 0; nn < NREG; ++nn)
    outp[(size_t)nn * NM] = (uint16_t)acc[nn];
}

// ---------------- integer scan: sums 4 u16 SAD-planes; arithmetic scaled by
// 255 (no division). Emits split A/E u16 planes for the next layer:
// a16 = x?1:-1 ; e16 = x? ~p : p.
template<int NOUT, int KD, int OFF2, int LOGN>
__global__ __launch_bounds__(64) void k_scanv4(
    const uint16_t* __restrict__ Yp, const uint32_t* __restrict__ bb,
    uint16_t* __restrict__ Aout, uint16_t* __restrict__ Eout)
{
  const size_t PS = (size_t)NOUT * NM;
  int g = blockIdx.x * 64 + threadIdx.x;
  int o = g & (NOUT - 1);
  int b = g >> LOGN;
  const uint16_t* row = Yp + (size_t)o * NM + b * 256;
  const int C = 255 * (2 * KD - OFF2);
  int inA = 0, outA = 0, cA = 0, cum = 0;
  uint4 c0 = *(const uint4*)(row);
  uint4 c1 = *(const uint4*)(row + PS);
  uint4 c2 = *(const uint4*)(row + 2 * PS);
  uint4 c3 = *(const uint4*)(row + 3 * PS);
  #pragma unroll
  for (int w = 0; w < 8; ++w) {
    uint32_t bwc = bb[o * 8 + w];
    #pragma unroll
    for (int cchunk = 0; cchunk < 4; ++cchunk) {
      int t0 = w * 32 + cchunk * 8;
      uint4 n0v = c0, n1v = c1, n2v = c2, n3v = c3;
      if (t0 < 248) {
        n0v = *(const uint4*)(row + t0 + 8);
        n1v = *(const uint4*)(row + PS + t0 + 8);
        n2v = *(const uint4*)(row + 2 * PS + t0 + 8);
        n3v = *(const uint4*)(row + 3 * PS + t0 + 8);
      }
      uint32_t s[8];
      SUMLOHI(c0.x, c1.x, c2.x, c3.x, s[0], s[1]);
      SUMLOHI(c0.y, c1.y, c2.y, c3.y, s[2], s[3]);
      SUMLOHI(c0.z, c1.z, c2.z, c3.z, s[4], s[5]);
      SUMLOHI(c0.w, c1.w, c2.w, c3.w, s[6], s[7]);
      #pragma unroll
      for (int j = 0; j < 8; ++j) {
        int t = t0 + j;
        int bit = (int)((bwc >> (t & 31)) & 1u);
        inA += C + 510 * bit - 2 * (int)s[j];
        int outb = (inA > outA) ? 1 : 0;
        outA += 510 * outb;
        int a = (cA < 0) ? 1 : outb;
        cA += 1020 * a - 510;
        int idx = a ? cum : (t - cum);
        cum += a;
        uint32_t p = perm8(idx);
        size_t off = (size_t)(b * 256 + t) * NOUT + o;
        Aout[off] = a ? (uint16_t)1 : (uint16_t)0xFFFF;
        Eout[off] = a ? (uint16_t)(~p) : (uint16_t)p;
      }
      c0 = n0v; c1 = n1v; c2 = n2v; c3 = n3v;
    }
  }
}

// ------------------------------------ layer 3 (OUT=10), split A/E input,
// transposed output y3t[(b*16+o)*256 + t].
__global__ __launch_bounds__(256) void k_l3(
    const uint16_t* __restrict__ A3, const uint16_t* __restrict__ E3,
    const uint32_t* __restrict__ T3t, uint16_t* __restrict__ y3t)
{
  __shared__ uint32_t T3s[128][16];    // [kp][o]
  __shared__ uint32_t UFs3[16][258];   // [m][2*kp + {a,e}]
  int tid = threadIdx.x;
  int m0 = blockIdx.x * 16;
  const uint32_t c15 = 0x000F000Fu;
  for (int j = tid; j < 2048; j += 256) {
    int kp = j >> 4, o2 = j & 15;
    T3s[kp][o2] = (o2 < 10) ? T3t[kp * 10 + o2] : 0u;
  }
  { int row = tid >> 4, part = tid & 15;
    const uint4* as = (const uint4*)(A3 + (size_t)(m0 + row) * 256 + part * 16);
    const uint4* es = (const uint4*)(E3 + (size_t)(m0 + row) * 256 + part * 16);
    uint4 aA = as[0], aB = as[1];      // 8 a-pair words
    uint4 eA = es[0], eB = es[1];
    uint32_t o[16] = {aA.x, eA.x, aA.y, eA.y, aA.z, eA.z, aA.w, eA.w,
                      aB.x, eB.x, aB.y, eB.y, aB.z, eB.z, aB.w, eB.w};
    #pragma unroll
    for (int q4 = 0; q4 < 4; ++q4)
      *(uint4*)&UFs3[row][part * 16 + q4 * 4] =
          make_uint4(o[q4 * 4], o[q4 * 4 + 1], o[q4 * 4 + 2], o[q4 * 4 + 3]);
  }
  __syncthreads();
  int mr = tid >> 4, o = tid & 15;
  uint32_t acc = 0;
  #pragma unroll 4
  for (int kp2 = 0; kp2 < 64; ++kp2) {
    uint4 uf = *(const uint4*)&UFs3[mr][kp2 * 4];
    qstep3(acc, T3s[2 * kp2][o],     uf.x, uf.y, c15);
    qstep3(acc, T3s[2 * kp2 + 1][o], uf.z, uf.w, c15);
  }
  if (o < 10) {
    int mm = m0 + mr;
    int b = mm >> 8, t = mm & 255;
    y3t[(size_t)(b * 16 + o) * 256 + t] =
        (uint16_t)(256 + (short)(acc & 0xFFFFu) + (short)(acc >> 16));
  }
}

// ---------------- layer-3 scan (contiguous y3t rows, uint4 prefetch)
// + log_softmax, fused
__global__ __launch_bounds__(256) void k_scan3sm(
    const uint16_t* __restrict__ y3t, const uint32_t* __restrict__ bb3,
    const float* __restrict__ pred, float* __restrict__ out)
{
  __shared__ uint32_t obl[16][16][8];
  __shared__ float prs[160];
  int tid = threadIdx.x;
  if (tid < 160) prs[tid] = pred[tid];
  int b = tid >> 4, o = tid & 15;
  if (o < 10) {
    const uint16_t* row = y3t + (size_t)(b * 16 + o) * 256;
    int in2 = 0, out2 = 0;
    uint4 cur = *(const uint4*)row;
    #pragma unroll
    for (int w = 0; w < 8; ++w) {
      uint32_t bwc = bb3[o * 8 + w];
      uint32_t bits = 0;
      #pragma unroll
      for (int cchunk = 0; cchunk < 4; ++cchunk) {
        int t0 = w * 32 + cchunk * 8;
        uint4 nxt = cur;
        if (t0 < 248) nxt = *(const uint4*)(row + t0 + 8);
        uint32_t cw[4] = {cur.x, cur.y, cur.z, cur.w};
        #pragma unroll
        for (int j = 0; j < 8; ++j) {
          int t = t0 + j;
          int cnt = (int)((cw[j >> 1] >> ((j & 1) * 16)) & 0xFFFFu);
          in2 += 2 * cnt + 2 * (int)((bwc >> (t & 31)) & 1u) - 255;
          int outb = (in2 > out2) ? 1 : 0;
          out2 += outb << 1;
          bits |= (uint32_t)outb << (t & 31);
        }
        cur = nxt;
      }
      obl[b][o][w] = bits;
    }
  }
  __syncthreads();
  for (int r = tid; r < 4096; r += 256) {
    int t = r >> 4, b2 = r & 15;
    float z[10], mx = -3e38f;
    #pragma unroll
    for (int oo = 0; oo < 10; ++oo) {
      int bit = (obl[b2][oo][t >> 5] >> (t & 31)) & 1;
      z[oo] = (bit ? 1.f : -1.f) - prs[b2 * 10 + oo];
      mx = fmaxf(mx, z[oo]);
    }
    float s = 0.f;
    #pragma unroll
    for (int oo = 0; oo < 10; ++oo) s += expf(z[oo] - mx);
    float ls = logf(s);
    float* op = out + (size_t)r * 10;       // r = t*16+b  ==  (t*NB+b)
    #pragma unroll
    for (int oo = 0; oo < 10; ++oo) op[oo] = z[oo] - mx - ls;
  }
}

// ---------------------------------------------------------------------------
extern "C" void kernel_launch(void* const* d_in, const int* in_sizes, int n_in,
                              void* d_out, int out_size, void* d_ws, size_t ws_size,
                              hipStream_t stream) {
  (void)in_sizes; (void)n_in; (void)out_size; (void)ws_size;
  const float* w1   = (const float*)d_in[0];
  const float* b1   = (const float*)d_in[1];
  const float* w2   = (const float*)d_in[2];
  const float* b2   = (const float*)d_in[3];
  const float* w3   = (const float*)d_in[4];
  const float* b3   = (const float*)d_in[5];
  const float* pred = (const float*)d_in[6];
  const int*   x    = (const int*)d_in[7];
  float* out = (float*)d_out;
  uint8_t* W = (uint8_t*)d_ws;

  uint32_t* T1   = (uint32_t*)(W + 0);          // 1 MB  chunk layout
  uint32_t* T2   = (uint32_t*)(W + 1048576);    // 256 KB chunk layout
  uint32_t* T3t  = (uint32_t*)(W + 1310720);    // 8 KB  [128 kp][10 n]
  uint32_t* bb1  = (uint32_t*)(W + 1318912);    // 16 KB
  uint32_t* bb2  = (uint32_t*)(W + 1335296);    // 8 KB
  uint32_t* bb3  = (uint32_t*)(W + 1343488);    // 512 B
  uint16_t* chks = (uint16_t*)(W + 1344000);    // 256 KB          end 1606144
  // AE1: 16 MB, dead after gemm1.
  uint2*    AE1  = (uint2*)   (W + 1606144);    // 1606144 .. 18383360
  // Yp1 ABOVE AE1 (both live during gemm1): 4 planes x 4 MB
  uint16_t* Yp1  = (uint16_t*)(W + 18383360);   // 18383360 .. 35160576
  // aliases inside dead AE1 region (valid after gemm1 completes):
  uint16_t* A2   = (uint16_t*)(W + 1606144);    // 4 MB
  uint16_t* E2   = (uint16_t*)(W + 5800448);    // 4 MB
  uint16_t* A3   = (uint16_t*)(W + 9994752);    // 2 MB
  uint16_t* E3   = (uint16_t*)(W + 12091904);   // 2 MB
  uint16_t* y3t  = (uint16_t*)(W + 14189056);   // 128 KB (ends 14320128)
  uint16_t* Yp2  = Yp1;                         // 4 planes x 2 MB (Yp1 dead)
  // peak end = 35160576 (~33.5 MB) < 47.7 MB proven in R5

  hipLaunchKernelGGL(k_prepA, dim3(1822), dim3(256), 0, stream,
                     w1, w2, w3, b1, b2, b3, x, T1, T2, T3t, bb1, bb2, bb3, chks);
  hipLaunchKernelGGL(k_prep1ae, dim3(256), dim3(256), 0, stream, x, chks, AE1);
  hipLaunchKernelGGL((k_gemmv6<1024, 512, 16, 256>), dim3(16, 32, 4), dim3(256),
                     0, stream, AE1, T1, Yp1);
  hipLaunchKernelGGL((k_scanv4<512, 1024, 1023, 9>), dim3(128), dim3(64), 0,
                     stream, Yp1, bb1, A2, E2);
  hipLaunchKernelGGL((k_gemmv6b<512, 256, 16, 128>), dim3(16, 16, 4), dim3(256),
                     0, stream, A2, E2, T2, Yp2);
  hipLaunchKernelGGL((k_scanv4<256, 512, 511, 8>), dim3(64), dim3(64), 0,
                     stream, Yp2, bb2, A3, E3);
  hipLaunchKernelGGL(k_l3, dim3(256), dim3(256), 0, stream, A3, E3, T3t, y3t);
  hipLaunchKernelGGL(k_scan3sm, dim3(1), dim3(256), 0, stream, y3t, bb3, pred, out);
}

// Round 17
// 200.805 us; speedup vs baseline: 1.0609x; 1.0609x over previous
//
#include <hip/hip_runtime.h>
#include <stdint.h>

#define TSTEPS 256
#define NB 16
#define NM (TSTEPS*NB)   // 4096

typedef short s16x2 __attribute__((ext_vector_type(2)));

// perm(i) = bitrev8(gray(i)) : the Sobol value rng[i] = 2*perm8(i)/256 - 1
__device__ __forceinline__ uint32_t perm8(int i) {
  uint32_t g = (uint32_t)(i ^ (i >> 1));
  return __brev(g) >> 24;
}

// z = a*t + e (packed i16), t wave-uniform in SGPR
__device__ __forceinline__ void qmad(uint32_t& z, uint32_t a, uint32_t t_s,
                                     uint32_t e) {
  asm("v_pk_mad_i16 %0, %1, %2, %3" : "=v"(z) : "v"(a), "s"(t_s), "v"(e));
}
__device__ __forceinline__ uint32_t qperm(uint32_t x, uint32_t y, uint32_t sel) {
  uint32_t d;
  asm("v_perm_b32 %0, %1, %2, %3" : "=v"(d) : "v"(x), "v"(y), "v"(sel));
  return d;
}
// acc += byte0+byte1+byte2+byte3 of p  (each byte is 0x00 or 0xFF exactly)
__device__ __forceinline__ void qsad(uint32_t& acc, uint32_t p) {
  asm("v_sad_u8 %0, %1, 0, %0" : "+v"(acc) : "v"(p));
}

// all-VGPR compare step (l3 only)
__device__ __forceinline__ void qstep3(uint32_t& acc, uint32_t t2, uint32_t a2,
                                       uint32_t e2, uint32_t c15) {
  uint32_t z;
  asm("v_pk_mad_i16 %0, %2, %3, %4\n\t"
      "v_pk_ashrrev_i16 %0, %5, %0\n\t"
      "v_pk_add_i16 %1, %1, %0"
      : "=&v"(z), "+v"(acc)
      : "v"(a2), "v"(t2), "v"(e2), "v"(c15));
}

__device__ __forceinline__ uint32_t pkadd16(uint32_t a, uint32_t b) {
  return __builtin_bit_cast(uint32_t,
        (s16x2)(__builtin_bit_cast(s16x2, a) + __builtin_bit_cast(s16x2, b)));
}

// unpack packed v16 (u | xbar<<15) pair -> (a2, e2)
__device__ __forceinline__ void unpackAE(uint32_t v2, uint32_t& a2, uint32_t& e2) {
  s16x2 sv = __builtin_bit_cast(s16x2, v2) >> 15;      // 0 / -1 per half (xbar)
  uint32_t su = __builtin_bit_cast(uint32_t, sv);
  uint32_t vand = v2 & 0x01FF01FFu;
  e2 = pkadd16(~vand, su & 0x01FF01FFu);
  a2 = pkadd16(0x00010001u, pkadd16(su, su));          // +1 / -1
}

__device__ __forceinline__ int rank256(float w) {
  double v = 128.0 * (double)w + 128.0;
  int t = (int)ceil(v);
  if (t < 0) t = 0; if (t > 256) t = 256;
  return t;
}

#define SUMLOHI(A,B,C,D, LO, HI) \
  LO = (A & 0xFFFFu) + (B & 0xFFFFu) + (C & 0xFFFFu) + (D & 0xFFFFu); \
  HI = (A >> 16) + (B >> 16) + (C >> 16) + (D >> 16);

// ----------------- fused prep: rank tables + bias bitmasks + x chunk sums
// T1/T2 CHUNK-INTERLEAVED layout: Tc[(kp>>2)*NT + n]*4 + (kp&3).
__global__ __launch_bounds__(256) void k_prepA(
    const float* __restrict__ w1, const float* __restrict__ w2,
    const float* __restrict__ w3, const float* __restrict__ b1,
    const float* __restrict__ b2, const float* __restrict__ b3,
    const int* __restrict__ x,
    uint32_t* __restrict__ T1, uint32_t* __restrict__ T2,
    uint32_t* __restrict__ T3t, uint32_t* __restrict__ bb1,
    uint32_t* __restrict__ bb2, uint32_t* __restrict__ bb3,
    uint16_t* __restrict__ cs)
{
  int bid = blockIdx.x, tid = threadIdx.x;
  if (bid < 1024) {                      // w1 -> T1c chunk layout (512 n, 512 kp)
    int e = bid * 256 + tid;             // e = n*512 + kp
    int n = e >> 9, kp = e & 511;
    int dst = ((kp >> 2) * 512 + n) * 4 + (kp & 3);
    T1[dst] = (uint32_t)rank256(w1[2 * e]) |
              ((uint32_t)rank256(w1[2 * e + 1]) << 16);
  } else if (bid < 1280) {               // w2 -> T2c chunk layout (256 n, 256 kp)
    int e = (bid - 1024) * 256 + tid;    // e = n*256 + kp
    int n = e >> 8, kp = e & 255;
    int dst = ((kp >> 2) * 256 + n) * 4 + (kp & 3);
    T2[dst] = (uint32_t)rank256(w2[2 * e]) |
              ((uint32_t)rank256(w2[2 * e + 1]) << 16);
  } else if (bid < 1285) {               // w3 -> T3t [128 kp][10 n]
    int e = (bid - 1280) * 256 + tid;
    if (e < 1280) {
      int n = e % 10, kp = e / 10;
      T3t[e] = (uint32_t)rank256(w3[n * 256 + 2 * kp]) |
               ((uint32_t)rank256(w3[n * 256 + 2 * kp + 1]) << 16);
    }
  } else if (bid < 1301) {               // bb1: 512 o x 8 words
    int w = (bid - 1285) * 256 + tid;
    int o = w >> 3, j = w & 7;
    double bv = (double)b1[o] * 128.0 + 128.0;
    uint32_t bits = 0;
    for (int s = 0; s < 32; ++s)
      if (bv > (double)perm8(j * 32 + s)) bits |= 1u << s;
    bb1[w] = bits;
  } else if (bid < 1309) {               // bb2: 256 o x 8 words
    int w = (bid - 1301) * 256 + tid;
    int o = w >> 3, j = w & 7;
    double bv = (double)b2[o] * 128.0 + 128.0;
    uint32_t bits = 0;
    for (int s = 0; s < 32; ++s)
      if (bv > (double)perm8(j * 32 + s)) bits |= 1u << s;
    bb2[w] = bits;
  } else if (bid == 1309) {              // bb3: 10 o x 8 words
    if (tid < 80) {
      int o = tid >> 3, j = tid & 7;
      double bv = (double)b3[o] * 128.0 + 128.0;
      uint32_t bits = 0;
      for (int s = 0; s < 32; ++s)
        if (bv > (double)perm8(j * 32 + s)) bits |= 1u << s;
      bb3[tid] = bits;
    }
  } else {                               // x chunk sums (512 blocks)
    int g = (bid - 1310) * 256 + tid;
    int i = g & 1023, b = (g >> 10) & 15, c = g >> 14;
    int s = 0, t0 = c * 32;
    for (int tt = t0; tt < t0 + 32; ++tt)
      s += x[((size_t)tt * NB + b) * 1024 + i];
    cs[(c * NB + b) * 1024 + i] = (uint16_t)s;
  }
}

// ------------- layer-1 AE build (m = b*256+t): each thread owns an i-PAIR,
// stores (a2,e2) via the SAME unpackAE bit path the GEMM used.
__global__ __launch_bounds__(256) void k_prep1ae(const int* __restrict__ x,
                                                 const uint16_t* __restrict__ cs,
                                                 uint2* __restrict__ AE1) {
  int g = blockIdx.x * 256 + threadIdx.x;       // 65536
  int ip = g & 511;                             // i-pair
  int b = (g >> 9) & 15, c = g >> 13;           // c in 0..7
  int i0 = 2 * ip;
  int cum0 = 0, cum1 = 0;
  for (int cc = 0; cc < c; ++cc) {
    uint32_t two = *(const uint32_t*)(cs + (cc * NB + b) * 1024 + i0);
    cum0 += (int)(two & 0xFFFFu);
    cum1 += (int)(two >> 16);
  }
  int t0 = c * 32;
  for (int tt = t0; tt < t0 + 32; ++tt) {
    int m = b * 256 + tt;
    int2 xv = *(const int2*)(x + ((size_t)tt * NB + b) * 1024 + i0);
    int idx0 = xv.x ? cum0 : (tt - cum0);
    int idx1 = xv.y ? cum1 : (tt - cum1);
    uint32_t p0 = perm8(idx0), p1 = perm8(idx1);
    uint32_t v0 = (xv.x ? p0 : (510u - p0)) | ((uint32_t)(xv.x ^ 1) << 15);
    uint32_t v1 = (xv.y ? p1 : (510u - p1)) | ((uint32_t)(xv.y ^ 1) << 15);
    uint32_t a2, e2;
    unpackAE(v0 | (v1 << 16), a2, e2);
    AE1[(size_t)m * 512 + ip] = make_uint2(a2, e2);
    cum0 += xv.x; cum1 += xv.y;
  }
}

// ---------------- perm+SAD GEMM layer 1, MREG=2: each thread computes rows
// m and m+2048, sharing the per-chunk T SGPR batch -> 256 VALU insts per
// SMEM batch (vs 128), halving the relative SMEM-latency stall (R16).
template<int KD, int NT, int NREG, int KC>
__global__ __launch_bounds__(256, 4) void k_gemmv7(
    const uint2* __restrict__ AE, const uint32_t* __restrict__ T,
    uint16_t* __restrict__ Yp)
{
  const int tid = threadIdx.x;
  const int m0 = blockIdx.x * 256 + tid;        // bx in 0..7
  const int m1 = m0 + 2048;
  const int n0 = blockIdx.y * NREG;
  const int sk = blockIdx.z;
  const int k0 = sk * KC;
  uint32_t sel = 0x07050301u;
  uint32_t accA[NREG], accB[NREG];
  #pragma unroll
  for (int nn = 0; nn < NREG; ++nn) { accA[nn] = 0; accB[nn] = 0; }
  const uint4* vsrc0 = (const uint4*)(AE + (size_t)m0 * (KD / 2) + (k0 >> 1));
  const uint4* vsrc1 = (const uint4*)(AE + (size_t)m1 * (KD / 2) + (k0 >> 1));
  const uint32_t* tcbase = T + ((size_t)(k0 >> 3) * NT + n0) * 4;
  #pragma unroll 1
  for (int c = 0; c < KC / 8; ++c) {
    uint4 wa01 = vsrc0[2 * c], wa23 = vsrc0[2 * c + 1];
    uint4 wb01 = vsrc1[2 * c], wb23 = vsrc1[2 * c + 1];
    uint32_t a0 = wa01.x, e0 = wa01.y, a1 = wa01.z, e1 = wa01.w;
    uint32_t a2v = wa23.x, e2v = wa23.y, a3 = wa23.z, e3 = wa23.w;
    uint32_t f0 = wb01.x, g0 = wb01.y, f1 = wb01.z, g1 = wb01.w;
    uint32_t f2 = wb23.x, g2 = wb23.y, f3 = wb23.z, g3 = wb23.w;
    // pin: one load per chunk, shared by all NREG chains (R9/R10 lesson)
    asm volatile("" : "+v"(a0), "+v"(e0), "+v"(a1), "+v"(e1),
                      "+v"(a2v), "+v"(e2v), "+v"(a3), "+v"(e3),
                      "+v"(f0), "+v"(g0), "+v"(f1), "+v"(g1),
                      "+v"(f2), "+v"(g2), "+v"(f3), "+v"(g3));
    const uint4* tcp = (const uint4*)(tcbase + (size_t)c * NT * 4);
    uint4 tw[NREG];
    #pragma unroll
    for (int nn = 0; nn < NREG; ++nn) tw[nn] = tcp[nn];  // contiguous SMEM
    #pragma unroll
    for (int nn = 0; nn < NREG; ++nn) {
      uint32_t z0, z1, z2, z3;
      qmad(z0, a0, tw[nn].x, e0);
      qmad(z1, a1, tw[nn].y, e1);
      qmad(z2, a2v, tw[nn].z, e2v);
      qmad(z3, a3, tw[nn].w, e3);
      qsad(accA[nn], qperm(z0, z1, sel));
      qsad(accA[nn], qperm(z2, z3, sel));
      qmad(z0, f0, tw[nn].x, g0);
      qmad(z1, f1, tw[nn].y, g1);
      qmad(z2, f2, tw[nn].z, g2);
      qmad(z3, f3, tw[nn].w, g3);
      qsad(accB[nn], qperm(z0, z1, sel));
      qsad(accB[nn], qperm(z2, z3, sel));
    }
  }
  uint16_t* outp = Yp + ((size_t)sk * NT + n0) * (size_t)NM;
  #pragma unroll
  for (int nn = 0; nn < NREG; ++nn) {
    outp[(size_t)nn * NM + m0] = (uint16_t)accA[nn];
    outp[(size_t)nn * NM + m1] = (uint16_t)accB[nn];
  }
}

// ---------------- perm+SAD GEMM layer 2: V-format operand (unpack per
// chunk, R13-proven), chunk-layout T.
template<int KD, int NT, int NREG, int KC>
__global__ __launch_bounds__(256, 4) void k_gemmv5c(
    const uint16_t* __restrict__ V, const uint32_t* __restrict__ T,
    uint16_t* __restrict__ Yp)
{
  const int tid = threadIdx.x;
  const int m = blockIdx.x * 256 + tid;
  const int n0 = blockIdx.y * NREG;
  const int sk = blockIdx.z;
  const int k0 = sk * KC;
  uint32_t sel = 0x07050301u;
  uint32_t acc[NREG];
  #pragma unroll
  for (int nn = 0; nn < NREG; ++nn) acc[nn] = 0;
  const uint4* vsrc = (const uint4*)(V + (size_t)m * KD + k0);
  const uint32_t* tcbase = T + ((size_t)(k0 >> 3) * NT + n0) * 4;
  #pragma unroll 1
  for (int c = 0; c < KC / 8; ++c) {
    uint4 vv = vsrc[c];
    uint32_t a0, e0, a1, e1, a2v, e2v, a3, e3;
    unpackAE(vv.x, a0, e0);
    unpackAE(vv.y, a1, e1);
    unpackAE(vv.z, a2v, e2v);
    unpackAE(vv.w, a3, e3);
    asm volatile("" : "+v"(a0), "+v"(e0), "+v"(a1), "+v"(e1),
                      "+v"(a2v), "+v"(e2v), "+v"(a3), "+v"(e3));
    const uint4* tcp = (const uint4*)(tcbase + (size_t)c * NT * 4);
    uint4 tw[NREG];
    #pragma unroll
    for (int nn = 0; nn < NREG; ++nn) tw[nn] = tcp[nn];
    #pragma unroll
    for (int nn = 0; nn < NREG; ++nn) {
      uint32_t z0, z1, z2, z3;
      qmad(z0, a0, tw[nn].x, e0);
      qmad(z1, a1, tw[nn].y, e1);
      qmad(z2, a2v, tw[nn].z, e2v);
      qmad(z3, a3, tw[nn].w, e3);
      qsad(acc[nn], qperm(z0, z1, sel));
      qsad(acc[nn], qperm(z2, z3, sel));
    }
  }
  uint16_t* outp = Yp + ((size_t)sk * NT + n0) * (size_t)NM + m;
  #pragma unroll
  for (int nn = 0; nn < NREG; ++nn)
    outp[(size_t)nn * NM] = (uint16_t)acc[nn];
}

// ---------------- integer scan: sums 4 u16 SAD-planes; arithmetic scaled by
// 255 (no division). Emits packed V (R13-proven path).
template<int NOUT, int KD, int OFF2, int LOGN>
__global__ __launch_bounds__(64) void k_scanv3(
    const uint16_t* __restrict__ Yp, const uint32_t* __restrict__ bb,
    uint16_t* __restrict__ Vn)
{
  const size_t PS = (size_t)NOUT * NM;
  int g = blockIdx.x * 64 + threadIdx.x;
  int o = g & (NOUT - 1);
  int b = g >> LOGN;
  const uint16_t* row = Yp + (size_t)o * NM + b * 256;
  const int C = 255 * (2 * KD - OFF2);
  int inA = 0, outA = 0, cA = 0, cum = 0;
  uint4 c0 = *(const uint4*)(row);
  uint4 c1 = *(const uint4*)(row + PS);
  uint4 c2 = *(const uint4*)(row + 2 * PS);
  uint4 c3 = *(const uint4*)(row + 3 * PS);
  #pragma unroll
  for (int w = 0; w < 8; ++w) {
    uint32_t bwc = bb[o * 8 + w];
    #pragma unroll
    for (int cchunk = 0; cchunk < 4; ++cchunk) {
      int t0 = w * 32 + cchunk * 8;
      uint4 n0v = c0, n1v = c1, n2v = c2, n3v = c3;
      if (t0 < 248) {
        n0v = *(const uint4*)(row + t0 + 8);
        n1v = *(const uint4*)(row + PS + t0 + 8);
        n2v = *(const uint4*)(row + 2 * PS + t0 + 8);
        n3v = *(const uint4*)(row + 3 * PS + t0 + 8);
      }
      uint32_t s[8];
      SUMLOHI(c0.x, c1.x, c2.x, c3.x, s[0], s[1]);
      SUMLOHI(c0.y, c1.y, c2.y, c3.y, s[2], s[3]);
      SUMLOHI(c0.z, c1.z, c2.z, c3.z, s[4], s[5]);
      SUMLOHI(c0.w, c1.w, c2.w, c3.w, s[6], s[7]);
      #pragma unroll
      for (int j = 0; j < 8; ++j) {
        int t = t0 + j;
        int bit = (int)((bwc >> (t & 31)) & 1u);
        inA += C + 510 * bit - 2 * (int)s[j];
        int outb = (inA > outA) ? 1 : 0;
        outA += 510 * outb;
        int a = (cA < 0) ? 1 : outb;
        cA += 1020 * a - 510;
        int idx = a ? cum : (t - cum);
        cum += a;
        uint32_t p = perm8(idx);
        Vn[(size_t)(b * 256 + t) * NOUT + o] =
            (uint16_t)((a ? p : (510u - p)) | ((uint32_t)(a ^ 1) << 15));
      }
      c0 = n0v; c1 = n1v; c2 = n2v; c3 = n3v;
    }
  }
}

// ------------------------------------ layer 3 (OUT=10), V-format input,
// transposed output y3t[(b*16+o)*256 + t].
__global__ __launch_bounds__(256) void k_l3(
    const uint16_t* __restrict__ V3, const uint32_t* __restrict__ T3t,
    uint16_t* __restrict__ y3t)
{
  __shared__ uint32_t T3s[128][16];    // [kp][o]
  __shared__ uint32_t UFs3[16][258];   // [m][2*kp + {a,e}]
  int tid = threadIdx.x;
  int m0 = blockIdx.x * 16;
  const uint32_t c15 = 0x000F000Fu;
  for (int j = tid; j < 2048; j += 256) {
    int kp = j >> 4, o2 = j & 15;
    T3s[kp][o2] = (o2 < 10) ? T3t[kp * 10 + o2] : 0u;
  }
  { int row = tid >> 4, part = tid & 15;
    const uint4* src = (const uint4*)(V3 + (size_t)(m0 + row) * 256 + part * 16);
    uint4 pa = src[0], pb = src[1];
    uint32_t w[8] = {pa.x, pa.y, pa.z, pa.w, pb.x, pb.y, pb.z, pb.w};
    uint32_t o[16];
    #pragma unroll
    for (int q = 0; q < 8; ++q) unpackAE(w[q], o[q * 2], o[q * 2 + 1]);
    #pragma unroll
    for (int q4 = 0; q4 < 4; ++q4)
      *(uint4*)&UFs3[row][part * 16 + q4 * 4] =
          make_uint4(o[q4 * 4], o[q4 * 4 + 1], o[q4 * 4 + 2], o[q4 * 4 + 3]);
  }
  __syncthreads();
  int mr = tid >> 4, o = tid & 15;
  uint32_t acc = 0;
  #pragma unroll 4
  for (int kp2 = 0; kp2 < 64; ++kp2) {
    uint4 uf = *(const uint4*)&UFs3[mr][kp2 * 4];
    qstep3(acc, T3s[2 * kp2][o],     uf.x, uf.y, c15);
    qstep3(acc, T3s[2 * kp2 + 1][o], uf.z, uf.w, c15);
  }
  if (o < 10) {
    int mm = m0 + mr;
    int b = mm >> 8, t = mm & 255;
    y3t[(size_t)(b * 16 + o) * 256 + t] =
        (uint16_t)(256 + (short)(acc & 0xFFFFu) + (short)(acc >> 16));
  }
}

// ---------------- layer-3 scan (contiguous y3t rows, uint4 prefetch)
// + log_softmax, fused
__global__ __launch_bounds__(256) void k_scan3sm(
    const uint16_t* __restrict__ y3t, const uint32_t* __restrict__ bb3,
    const float* __restrict__ pred, float* __restrict__ out)
{
  __shared__ uint32_t obl[16][16][8];
  __shared__ float prs[160];
  int tid = threadIdx.x;
  if (tid < 160) prs[tid] = pred[tid];
  int b = tid >> 4, o = tid & 15;
  if (o < 10) {
    const uint16_t* row = y3t + (size_t)(b * 16 + o) * 256;
    int in2 = 0, out2 = 0;
    uint4 cur = *(const uint4*)row;
    #pragma unroll
    for (int w = 0; w < 8; ++w) {
      uint32_t bwc = bb3[o * 8 + w];
      uint32_t bits = 0;
      #pragma unroll
      for (int cchunk = 0; cchunk < 4; ++cchunk) {
        int t0 = w * 32 + cchunk * 8;
        uint4 nxt = cur;
        if (t0 < 248) nxt = *(const uint4*)(row + t0 + 8);
        uint32_t cw[4] = {cur.x, cur.y, cur.z, cur.w};
        #pragma unroll
        for (int j = 0; j < 8; ++j) {
          int t = t0 + j;
          int cnt = (int)((cw[j >> 1] >> ((j & 1) * 16)) & 0xFFFFu);
          in2 += 2 * cnt + 2 * (int)((bwc >> (t & 31)) & 1u) - 255;
          int outb = (in2 > out2) ? 1 : 0;
          out2 += outb << 1;
          bits |= (uint32_t)outb << (t & 31);
        }
        cur = nxt;
      }
      obl[b][o][w] = bits;
    }
  }
  __syncthreads();
  for (int r = tid; r < 4096; r += 256) {
    int t = r >> 4, b2 = r & 15;
    float z[10], mx = -3e38f;
    #pragma unroll
    for (int oo = 0; oo < 10; ++oo) {
      int bit = (obl[b2][oo][t >> 5] >> (t & 31)) & 1;
      z[oo] = (bit ? 1.f : -1.f) - prs[b2 * 10 + oo];
      mx = fmaxf(mx, z[oo]);
    }
    float s = 0.f;
    #pragma unroll
    for (int oo = 0; oo < 10; ++oo) s += expf(z[oo] - mx);
    float ls = logf(s);
    float* op = out + (size_t)r * 10;       // r = t*16+b  ==  (t*NB+b)
    #pragma unroll
    for (int oo = 0; oo < 10; ++oo) op[oo] = z[oo] - mx - ls;
  }
}

// ---------------------------------------------------------------------------
extern "C" void kernel_launch(void* const* d_in, const int* in_sizes, int n_in,
                              void* d_out, int out_size, void* d_ws, size_t ws_size,
                              hipStream_t stream) {
  (void)in_sizes; (void)n_in; (void)out_size; (void)ws_size;
  const float* w1   = (const float*)d_in[0];
  const float* b1   = (const float*)d_in[1];
  const float* w2   = (const float*)d_in[2];
  const float* b2   = (const float*)d_in[3];
  const float* w3   = (const float*)d_in[4];
  const float* b3   = (const float*)d_in[5];
  const float* pred = (const float*)d_in[6];
  const int*   x    = (const int*)d_in[7];
  float* out = (float*)d_out;
  uint8_t* W = (uint8_t*)d_ws;

  uint32_t* T1   = (uint32_t*)(W + 0);          // 1 MB  chunk layout
  uint32_t* T2   = (uint32_t*)(W + 1048576);    // 256 KB chunk layout
  uint32_t* T3t  = (uint32_t*)(W + 1310720);    // 8 KB  [128 kp][10 n]
  uint32_t* bb1  = (uint32_t*)(W + 1318912);    // 16 KB
  uint32_t* bb2  = (uint32_t*)(W + 1335296);    // 8 KB
  uint32_t* bb3  = (uint32_t*)(W + 1343488);    // 512 B
  uint16_t* chks = (uint16_t*)(W + 1344000);    // 256 KB          end 1606144
  // AE1: 16 MB, dead after gemm1.
  uint2*    AE1  = (uint2*)   (W + 1606144);    // 1606144 .. 18383360
  // Yp1 ABOVE AE1 (both live during gemm1): 4 planes x 4 MB
  uint16_t* Yp1  = (uint16_t*)(W + 18383360);   // 18383360 .. 35160576
  // aliases inside dead AE1 region (valid after gemm1 completes):
  uint16_t* V2   = (uint16_t*)(W + 1606144);    // 4 MB
  uint16_t* V3   = (uint16_t*)(W + 5800448);    // 2 MB
  uint16_t* y3t  = (uint16_t*)(W + 7897600);    // 128 KB
  uint16_t* Yp2  = Yp1;                         // 4 planes x 2 MB (Yp1 dead)
  // peak end = 35160576 (~33.5 MB) < 47.7 MB proven in R5

  hipLaunchKernelGGL(k_prepA, dim3(1822), dim3(256), 0, stream,
                     w1, w2, w3, b1, b2, b3, x, T1, T2, T3t, bb1, bb2, bb3, chks);
  hipLaunchKernelGGL(k_prep1ae, dim3(256), dim3(256), 0, stream, x, chks, AE1);
  hipLaunchKernelGGL((k_gemmv7<1024, 512, 16, 256>), dim3(8, 32, 4), dim3(256),
                     0, stream, AE1, T1, Yp1);
  hipLaunchKernelGGL((k_scanv3<512, 1024, 1023, 9>), dim3(128), dim3(64), 0,
                     stream, Yp1, bb1, V2);
  hipLaunchKernelGGL((k_gemmv5c<512, 256, 16, 128>), dim3(16, 16, 4), dim3(256),
                     0, stream, V2, T2, Yp2);
  hipLaunchKernelGGL((k_scanv3<256, 512, 511, 8>), dim3(64), dim3(64), 0,
                     stream, Yp2, bb2, V3);
  hipLaunchKernelGGL(k_l3, dim3(256), dim3(256), 0, stream, V3, T3t, y3t);
  hipLaunchKernelGGL(k_scan3sm, dim3(1), dim3(256), 0, stream, y3t, bb3, pred, out);
}

// Round 18
// 194.727 us; speedup vs baseline: 1.0940x; 1.0312x over previous
//
#include <hip/hip_runtime.h>
#include <stdint.h>

#define TSTEPS 256
#define NB 16
#define NM (TSTEPS*NB)   // 4096

typedef short s16x2 __attribute__((ext_vector_type(2)));

// perm(i) = bitrev8(gray(i)) : the Sobol value rng[i] = 2*perm8(i)/256 - 1
__device__ __forceinline__ uint32_t perm8(int i) {
  uint32_t g = (uint32_t)(i ^ (i >> 1));
  return __brev(g) >> 24;
}

// z = a*t + e (packed i16), t wave-uniform in SGPR
__device__ __forceinline__ void qmad(uint32_t& z, uint32_t a, uint32_t t_s,
                                     uint32_t e) {
  asm("v_pk_mad_i16 %0, %1, %2, %3" : "=v"(z) : "v"(a), "s"(t_s), "v"(e));
}
__device__ __forceinline__ uint32_t qperm(uint32_t x, uint32_t y, uint32_t sel) {
  uint32_t d;
  asm("v_perm_b32 %0, %1, %2, %3" : "=v"(d) : "v"(x), "v"(y), "v"(sel));
  return d;
}
// acc += byte0+byte1+byte2+byte3 of p  (each byte is 0x00 or 0xFF exactly)
__device__ __forceinline__ void qsad(uint32_t& acc, uint32_t p) {
  asm("v_sad_u8 %0, %1, 0, %0" : "+v"(acc) : "v"(p));
}

// all-VGPR compare step (l3 only)
__device__ __forceinline__ void qstep3(uint32_t& acc, uint32_t t2, uint32_t a2,
                                       uint32_t e2, uint32_t c15) {
  uint32_t z;
  asm("v_pk_mad_i16 %0, %2, %3, %4\n\t"
      "v_pk_ashrrev_i16 %0, %5, %0\n\t"
      "v_pk_add_i16 %1, %1, %0"
      : "=&v"(z), "+v"(acc)
      : "v"(a2), "v"(t2), "v"(e2), "v"(c15));
}

__device__ __forceinline__ uint32_t pkadd16(uint32_t a, uint32_t b) {
  return __builtin_bit_cast(uint32_t,
        (s16x2)(__builtin_bit_cast(s16x2, a) + __builtin_bit_cast(s16x2, b)));
}

// unpack packed v16 (u | xbar<<15) pair -> (a2, e2)
__device__ __forceinline__ void unpackAE(uint32_t v2, uint32_t& a2, uint32_t& e2) {
  s16x2 sv = __builtin_bit_cast(s16x2, v2) >> 15;      // 0 / -1 per half (xbar)
  uint32_t su = __builtin_bit_cast(uint32_t, sv);
  uint32_t vand = v2 & 0x01FF01FFu;
  e2 = pkadd16(~vand, su & 0x01FF01FFu);
  a2 = pkadd16(0x00010001u, pkadd16(su, su));          // +1 / -1
}

__device__ __forceinline__ int rank256(float w) {
  double v = 128.0 * (double)w + 128.0;
  int t = (int)ceil(v);
  if (t < 0) t = 0; if (t > 256) t = 256;
  return t;
}

#define SUMLOHI(A,B,C,D, LO, HI) \
  LO = (A & 0xFFFFu) + (B & 0xFFFFu) + (C & 0xFFFFu) + (D & 0xFFFFu); \
  HI = (A >> 16) + (B >> 16) + (C >> 16) + (D >> 16);

// ----------------- fused prep: rank tables + bias bitmasks + x chunk sums
// T1/T2 CHUNK-INTERLEAVED layout: Tc[(kp>>2)*NT + n]*4 + (kp&3).
__global__ __launch_bounds__(256) void k_prepA(
    const float* __restrict__ w1, const float* __restrict__ w2,
    const float* __restrict__ w3, const float* __restrict__ b1,
    const float* __restrict__ b2, const float* __restrict__ b3,
    const int* __restrict__ x,
    uint32_t* __restrict__ T1, uint32_t* __restrict__ T2,
    uint32_t* __restrict__ T3t, uint32_t* __restrict__ bb1,
    uint32_t* __restrict__ bb2, uint32_t* __restrict__ bb3,
    uint16_t* __restrict__ cs)
{
  int bid = blockIdx.x, tid = threadIdx.x;
  if (bid < 1024) {                      // w1 -> T1c chunk layout (512 n, 512 kp)
    int e = bid * 256 + tid;             // e = n*512 + kp
    int n = e >> 9, kp = e & 511;
    int dst = ((kp >> 2) * 512 + n) * 4 + (kp & 3);
    T1[dst] = (uint32_t)rank256(w1[2 * e]) |
              ((uint32_t)rank256(w1[2 * e + 1]) << 16);
  } else if (bid < 1280) {               // w2 -> T2c chunk layout (256 n, 256 kp)
    int e = (bid - 1024) * 256 + tid;    // e = n*256 + kp
    int n = e >> 8, kp = e & 255;
    int dst = ((kp >> 2) * 256 + n) * 4 + (kp & 3);
    T2[dst] = (uint32_t)rank256(w2[2 * e]) |
              ((uint32_t)rank256(w2[2 * e + 1]) << 16);
  } else if (bid < 1285) {               // w3 -> T3t [128 kp][10 n]
    int e = (bid - 1280) * 256 + tid;
    if (e < 1280) {
      int n = e % 10, kp = e / 10;
      T3t[e] = (uint32_t)rank256(w3[n * 256 + 2 * kp]) |
               ((uint32_t)rank256(w3[n * 256 + 2 * kp + 1]) << 16);
    }
  } else if (bid < 1301) {               // bb1: 512 o x 8 words
    int w = (bid - 1285) * 256 + tid;
    int o = w >> 3, j = w & 7;
    double bv = (double)b1[o] * 128.0 + 128.0;
    uint32_t bits = 0;
    for (int s = 0; s < 32; ++s)
      if (bv > (double)perm8(j * 32 + s)) bits |= 1u << s;
    bb1[w] = bits;
  } else if (bid < 1309) {               // bb2: 256 o x 8 words
    int w = (bid - 1301) * 256 + tid;
    int o = w >> 3, j = w & 7;
    double bv = (double)b2[o] * 128.0 + 128.0;
    uint32_t bits = 0;
    for (int s = 0; s < 32; ++s)
      if (bv > (double)perm8(j * 32 + s)) bits |= 1u << s;
    bb2[w] = bits;
  } else if (bid == 1309) {              // bb3: 10 o x 8 words
    if (tid < 80) {
      int o = tid >> 3, j = tid & 7;
      double bv = (double)b3[o] * 128.0 + 128.0;
      uint32_t bits = 0;
      for (int s = 0; s < 32; ++s)
        if (bv > (double)perm8(j * 32 + s)) bits |= 1u << s;
      bb3[tid] = bits;
    }
  } else {                               // x chunk sums (512 blocks)
    int g = (bid - 1310) * 256 + tid;
    int i = g & 1023, b = (g >> 10) & 15, c = g >> 14;
    int s = 0, t0 = c * 32;
    for (int tt = t0; tt < t0 + 32; ++tt)
      s += x[((size_t)tt * NB + b) * 1024 + i];
    cs[(c * NB + b) * 1024 + i] = (uint16_t)s;
  }
}

// ------------- layer-1 AE build (m = b*256+t): each thread owns an i-PAIR,
// stores (a2,e2) via the SAME unpackAE bit path the GEMM used.
__global__ __launch_bounds__(256) void k_prep1ae(const int* __restrict__ x,
                                                 const uint16_t* __restrict__ cs,
                                                 uint2* __restrict__ AE1) {
  int g = blockIdx.x * 256 + threadIdx.x;       // 65536
  int ip = g & 511;                             // i-pair
  int b = (g >> 9) & 15, c = g >> 13;           // c in 0..7
  int i0 = 2 * ip;
  int cum0 = 0, cum1 = 0;
  for (int cc = 0; cc < c; ++cc) {
    uint32_t two = *(const uint32_t*)(cs + (cc * NB + b) * 1024 + i0);
    cum0 += (int)(two & 0xFFFFu);
    cum1 += (int)(two >> 16);
  }
  int t0 = c * 32;
  for (int tt = t0; tt < t0 + 32; ++tt) {
    int m = b * 256 + tt;
    int2 xv = *(const int2*)(x + ((size_t)tt * NB + b) * 1024 + i0);
    int idx0 = xv.x ? cum0 : (tt - cum0);
    int idx1 = xv.y ? cum1 : (tt - cum1);
    uint32_t p0 = perm8(idx0), p1 = perm8(idx1);
    uint32_t v0 = (xv.x ? p0 : (510u - p0)) | ((uint32_t)(xv.x ^ 1) << 15);
    uint32_t v1 = (xv.y ? p1 : (510u - p1)) | ((uint32_t)(xv.y ^ 1) << 15);
    uint32_t a2, e2;
    unpackAE(v0 | (v1 << 16), a2, e2);
    AE1[(size_t)m * 512 + ip] = make_uint2(a2, e2);
    cum0 += xv.x; cum1 += xv.y;
  }
}

// ---------------- perm+SAD GEMM layer 1 (R15 proven shape, 86.7us):
// interleaved-AE operand, chunk-layout T, unroll 1 + fence, NREG=16.
template<int KD, int NT, int NREG, int KC>
__global__ __launch_bounds__(256, 4) void k_gemmv6(
    const uint2* __restrict__ AE, const uint32_t* __restrict__ T,
    uint16_t* __restrict__ Yp)
{
  const int tid = threadIdx.x;
  const int m = blockIdx.x * 256 + tid;
  const int n0 = blockIdx.y * NREG;
  const int sk = blockIdx.z;
  const int k0 = sk * KC;
  uint32_t sel = 0x07050301u;
  uint32_t acc[NREG];
  #pragma unroll
  for (int nn = 0; nn < NREG; ++nn) acc[nn] = 0;
  const uint4* vsrc = (const uint4*)(AE + (size_t)m * (KD / 2) + (k0 >> 1));
  const uint32_t* tcbase = T + ((size_t)(k0 >> 3) * NT + n0) * 4;
  #pragma unroll 1
  for (int c = 0; c < KC / 8; ++c) {
    uint4 w01 = vsrc[2 * c];       // a0,e0,a1,e1
    uint4 w23 = vsrc[2 * c + 1];   // a2,e2,a3,e3
    uint32_t a0 = w01.x, e0 = w01.y, a1 = w01.z, e1 = w01.w;
    uint32_t a2v = w23.x, e2v = w23.y, a3 = w23.z, e3 = w23.w;
    // pin: one load per chunk, shared by all NREG chains (R9/R10 lesson)
    asm volatile("" : "+v"(a0), "+v"(e0), "+v"(a1), "+v"(e1),
                      "+v"(a2v), "+v"(e2v), "+v"(a3), "+v"(e3));
    const uint4* tcp = (const uint4*)(tcbase + (size_t)c * NT * 4);
    uint4 tw[NREG];
    #pragma unroll
    for (int nn = 0; nn < NREG; ++nn) tw[nn] = tcp[nn];  // contiguous SMEM
    #pragma unroll
    for (int nn = 0; nn < NREG; ++nn) {
      uint32_t z0, z1, z2, z3;
      qmad(z0, a0, tw[nn].x, e0);
      qmad(z1, a1, tw[nn].y, e1);
      qmad(z2, a2v, tw[nn].z, e2v);
      qmad(z3, a3, tw[nn].w, e3);
      qsad(acc[nn], qperm(z0, z1, sel));
      qsad(acc[nn], qperm(z2, z3, sel));
    }
  }
  uint16_t* outp = Yp + ((size_t)sk * NT + n0) * (size_t)NM + m;
  #pragma unroll
  for (int nn = 0; nn < NREG; ++nn)
    outp[(size_t)nn * NM] = (uint16_t)acc[nn];
}

// ---------------- perm+SAD GEMM layer 2: V-format operand (unpack per
// chunk, R13-proven), chunk-layout T.
template<int KD, int NT, int NREG, int KC>
__global__ __launch_bounds__(256, 4) void k_gemmv5c(
    const uint16_t* __restrict__ V, const uint32_t* __restrict__ T,
    uint16_t* __restrict__ Yp)
{
  const int tid = threadIdx.x;
  const int m = blockIdx.x * 256 + tid;
  const int n0 = blockIdx.y * NREG;
  const int sk = blockIdx.z;
  const int k0 = sk * KC;
  uint32_t sel = 0x07050301u;
  uint32_t acc[NREG];
  #pragma unroll
  for (int nn = 0; nn < NREG; ++nn) acc[nn] = 0;
  const uint4* vsrc = (const uint4*)(V + (size_t)m * KD + k0);
  const uint32_t* tcbase = T + ((size_t)(k0 >> 3) * NT + n0) * 4;
  #pragma unroll 1
  for (int c = 0; c < KC / 8; ++c) {
    uint4 vv = vsrc[c];
    uint32_t a0, e0, a1, e1, a2v, e2v, a3, e3;
    unpackAE(vv.x, a0, e0);
    unpackAE(vv.y, a1, e1);
    unpackAE(vv.z, a2v, e2v);
    unpackAE(vv.w, a3, e3);
    asm volatile("" : "+v"(a0), "+v"(e0), "+v"(a1), "+v"(e1),
                      "+v"(a2v), "+v"(e2v), "+v"(a3), "+v"(e3));
    const uint4* tcp = (const uint4*)(tcbase + (size_t)c * NT * 4);
    uint4 tw[NREG];
    #pragma unroll
    for (int nn = 0; nn < NREG; ++nn) tw[nn] = tcp[nn];
    #pragma unroll
    for (int nn = 0; nn < NREG; ++nn) {
      uint32_t z0, z1, z2, z3;
      qmad(z0, a0, tw[nn].x, e0);
      qmad(z1, a1, tw[nn].y, e1);
      qmad(z2, a2v, tw[nn].z, e2v);
      qmad(z3, a3, tw[nn].w, e3);
      qsad(acc[nn], qperm(z0, z1, sel));
      qsad(acc[nn], qperm(z2, z3, sel));
    }
  }
  uint16_t* outp = Yp + ((size_t)sk * NT + n0) * (size_t)NM + m;
  #pragma unroll
  for (int nn = 0; nn < NREG; ++nn)
    outp[(size_t)nn * NM] = (uint16_t)acc[nn];
}

// ---------------- integer scan: sums 4 u16 SAD-planes; arithmetic scaled by
// 255 (no division). Emits packed V (R13-proven path).
template<int NOUT, int KD, int OFF2, int LOGN>
__global__ __launch_bounds__(64) void k_scanv3(
    const uint16_t* __restrict__ Yp, const uint32_t* __restrict__ bb,
    uint16_t* __restrict__ Vn)
{
  const size_t PS = (size_t)NOUT * NM;
  int g = blockIdx.x * 64 + threadIdx.x;
  int o = g & (NOUT - 1);
  int b = g >> LOGN;
  const uint16_t* row = Yp + (size_t)o * NM + b * 256;
  const int C = 255 * (2 * KD - OFF2);
  int inA = 0, outA = 0, cA = 0, cum = 0;
  uint4 c0 = *(const uint4*)(row);
  uint4 c1 = *(const uint4*)(row + PS);
  uint4 c2 = *(const uint4*)(row + 2 * PS);
  uint4 c3 = *(const uint4*)(row + 3 * PS);
  #pragma unroll
  for (int w = 0; w < 8; ++w) {
    uint32_t bwc = bb[o * 8 + w];
    #pragma unroll
    for (int cchunk = 0; cchunk < 4; ++cchunk) {
      int t0 = w * 32 + cchunk * 8;
      uint4 n0v = c0, n1v = c1, n2v = c2, n3v = c3;
      if (t0 < 248) {
        n0v = *(const uint4*)(row + t0 + 8);
        n1v = *(const uint4*)(row + PS + t0 + 8);
        n2v = *(const uint4*)(row + 2 * PS + t0 + 8);
        n3v = *(const uint4*)(row + 3 * PS + t0 + 8);
      }
      uint32_t s[8];
      SUMLOHI(c0.x, c1.x, c2.x, c3.x, s[0], s[1]);
      SUMLOHI(c0.y, c1.y, c2.y, c3.y, s[2], s[3]);
      SUMLOHI(c0.z, c1.z, c2.z, c3.z, s[4], s[5]);
      SUMLOHI(c0.w, c1.w, c2.w, c3.w, s[6], s[7]);
      #pragma unroll
      for (int j = 0; j < 8; ++j) {
        int t = t0 + j;
        int bit = (int)((bwc >> (t & 31)) & 1u);
        inA += C + 510 * bit - 2 * (int)s[j];
        int outb = (inA > outA) ? 1 : 0;
        outA += 510 * outb;
        int a = (cA < 0) ? 1 : outb;
        cA += 1020 * a - 510;
        int idx = a ? cum : (t - cum);
        cum += a;
        uint32_t p = perm8(idx);
        Vn[(size_t)(b * 256 + t) * NOUT + o] =
            (uint16_t)((a ? p : (510u - p)) | ((uint32_t)(a ^ 1) << 15));
      }
      c0 = n0v; c1 = n1v; c2 = n2v; c3 = n3v;
    }
  }
}

// ------------------------------------ layer 3 (OUT=10), V-format input,
// transposed output y3t[(b*16+o)*256 + t].
__global__ __launch_bounds__(256) void k_l3(
    const uint16_t* __restrict__ V3, const uint32_t* __restrict__ T3t,
    uint16_t* __restrict__ y3t)
{
  __shared__ uint32_t T3s[128][16];    // [kp][o]
  __shared__ uint32_t UFs3[16][258];   // [m][2*kp + {a,e}]
  int tid = threadIdx.x;
  int m0 = blockIdx.x * 16;
  const uint32_t c15 = 0x000F000Fu;
  for (int j = tid; j < 2048; j += 256) {
    int kp = j >> 4, o2 = j & 15;
    T3s[kp][o2] = (o2 < 10) ? T3t[kp * 10 + o2] : 0u;
  }
  { int row = tid >> 4, part = tid & 15;
    const uint4* src = (const uint4*)(V3 + (size_t)(m0 + row) * 256 + part * 16);
    uint4 pa = src[0], pb = src[1];
    uint32_t w[8] = {pa.x, pa.y, pa.z, pa.w, pb.x, pb.y, pb.z, pb.w};
    uint32_t o[16];
    #pragma unroll
    for (int q = 0; q < 8; ++q) unpackAE(w[q], o[q * 2], o[q * 2 + 1]);
    #pragma unroll
    for (int q4 = 0; q4 < 4; ++q4)
      *(uint4*)&UFs3[row][part * 16 + q4 * 4] =
          make_uint4(o[q4 * 4], o[q4 * 4 + 1], o[q4 * 4 + 2], o[q4 * 4 + 3]);
  }
  __syncthreads();
  int mr = tid >> 4, o = tid & 15;
  uint32_t acc = 0;
  #pragma unroll 4
  for (int kp2 = 0; kp2 < 64; ++kp2) {
    uint4 uf = *(const uint4*)&UFs3[mr][kp2 * 4];
    qstep3(acc, T3s[2 * kp2][o],     uf.x, uf.y, c15);
    qstep3(acc, T3s[2 * kp2 + 1][o], uf.z, uf.w, c15);
  }
  if (o < 10) {
    int mm = m0 + mr;
    int b = mm >> 8, t = mm & 255;
    y3t[(size_t)(b * 16 + o) * 256 + t] =
        (uint16_t)(256 + (short)(acc & 0xFFFFu) + (short)(acc >> 16));
  }
}

// ---------------- layer-3 scan (contiguous y3t rows, uint4 prefetch)
// + log_softmax, fused
__global__ __launch_bounds__(256) void k_scan3sm(
    const uint16_t* __restrict__ y3t, const uint32_t* __restrict__ bb3,
    const float* __restrict__ pred, float* __restrict__ out)
{
  __shared__ uint32_t obl[16][16][8];
  __shared__ float prs[160];
  int tid = threadIdx.x;
  if (tid < 160) prs[tid] = pred[tid];
  int b = tid >> 4, o = tid & 15;
  if (o < 10) {
    const uint16_t* row = y3t + (size_t)(b * 16 + o) * 256;
    int in2 = 0, out2 = 0;
    uint4 cur = *(const uint4*)row;
    #pragma unroll
    for (int w = 0; w < 8; ++w) {
      uint32_t bwc = bb3[o * 8 + w];
      uint32_t bits = 0;
      #pragma unroll
      for (int cchunk = 0; cchunk < 4; ++cchunk) {
        int t0 = w * 32 + cchunk * 8;
        uint4 nxt = cur;
        if (t0 < 248) nxt = *(const uint4*)(row + t0 + 8);
        uint32_t cw[4] = {cur.x, cur.y, cur.z, cur.w};
        #pragma unroll
        for (int j = 0; j < 8; ++j) {
          int t = t0 + j;
          int cnt = (int)((cw[j >> 1] >> ((j & 1) * 16)) & 0xFFFFu);
          in2 += 2 * cnt + 2 * (int)((bwc >> (t & 31)) & 1u) - 255;
          int outb = (in2 > out2) ? 1 : 0;
          out2 += outb << 1;
          bits |= (uint32_t)outb << (t & 31);
        }
        cur = nxt;
      }
      obl[b][o][w] = bits;
    }
  }
  __syncthreads();
  for (int r = tid; r < 4096; r += 256) {
    int t = r >> 4, b2 = r & 15;
    float z[10], mx = -3e38f;
    #pragma unroll
    for (int oo = 0; oo < 10; ++oo) {
      int bit = (obl[b2][oo][t >> 5] >> (t & 31)) & 1;
      z[oo] = (bit ? 1.f : -1.f) - prs[b2 * 10 + oo];
      mx = fmaxf(mx, z[oo]);
    }
    float s = 0.f;
    #pragma unroll
    for (int oo = 0; oo < 10; ++oo) s += expf(z[oo] - mx);
    float ls = logf(s);
    float* op = out + (size_t)r * 10;       // r = t*16+b  ==  (t*NB+b)
    #pragma unroll
    for (int oo = 0; oo < 10; ++oo) op[oo] = z[oo] - mx - ls;
  }
}

// ---------------------------------------------------------------------------
extern "C" void kernel_launch(void* const* d_in, const int* in_sizes, int n_in,
                              void* d_out, int out_size, void* d_ws, size_t ws_size,
                              hipStream_t stream) {
  (void)in_sizes; (void)n_in; (void)out_size; (void)ws_size;
  const float* w1   = (const float*)d_in[0];
  const float* b1   = (const float*)d_in[1];
  const float* w2   = (const float*)d_in[2];
  const float* b2   = (const float*)d_in[3];
  const float* w3   = (const float*)d_in[4];
  const float* b3   = (const float*)d_in[5];
  const float* pred = (const float*)d_in[6];
  const int*   x    = (const int*)d_in[7];
  float* out = (float*)d_out;
  uint8_t* W = (uint8_t*)d_ws;

  uint32_t* T1   = (uint32_t*)(W + 0);          // 1 MB  chunk layout
  uint32_t* T2   = (uint32_t*)(W + 1048576);    // 256 KB chunk layout
  uint32_t* T3t  = (uint32_t*)(W + 1310720);    // 8 KB  [128 kp][10 n]
  uint32_t* bb1  = (uint32_t*)(W + 1318912);    // 16 KB
  uint32_t* bb2  = (uint32_t*)(W + 1335296);    // 8 KB
  uint32_t* bb3  = (uint32_t*)(W + 1343488);    // 512 B
  uint16_t* chks = (uint16_t*)(W + 1344000);    // 256 KB          end 1606144
  // AE1: 16 MB, dead after gemm1.
  uint2*    AE1  = (uint2*)   (W + 1606144);    // 1606144 .. 18383360
  // Yp1 ABOVE AE1 (both live during gemm1): 4 planes x 4 MB
  uint16_t* Yp1  = (uint16_t*)(W + 18383360);   // 18383360 .. 35160576
  // aliases inside dead AE1 region (valid after gemm1 completes):
  uint16_t* V2   = (uint16_t*)(W + 1606144);    // 4 MB
  uint16_t* V3   = (uint16_t*)(W + 5800448);    // 2 MB
  uint16_t* y3t  = (uint16_t*)(W + 7897600);    // 128 KB
  uint16_t* Yp2  = Yp1;                         // 4 planes x 2 MB (Yp1 dead)
  // peak end = 35160576 (~33.5 MB) < 47.7 MB proven in R5

  hipLaunchKernelGGL(k_prepA, dim3(1822), dim3(256), 0, stream,
                     w1, w2, w3, b1, b2, b3, x, T1, T2, T3t, bb1, bb2, bb3, chks);
  hipLaunchKernelGGL(k_prep1ae, dim3(256), dim3(256), 0, stream, x, chks, AE1);
  hipLaunchKernelGGL((k_gemmv6<1024, 512, 16, 256>), dim3(16, 32, 4), dim3(256),
                     0, stream, AE1, T1, Yp1);
  hipLaunchKernelGGL((k_scanv3<512, 1024, 1023, 9>), dim3(128), dim3(64), 0,
                     stream, Yp1, bb1, V2);
  hipLaunchKernelGGL((k_gemmv5c<512, 256, 16, 128>), dim3(16, 16, 4), dim3(256),
                     0, stream, V2, T2, Yp2);
  hipLaunchKernelGGL((k_scanv3<256, 512, 511, 8>), dim3(64), dim3(64), 0,
                     stream, Yp2, bb2, V3);
  hipLaunchKernelGGL(k_l3, dim3(256), dim3(256), 0, stream, V3, T3t, y3t);
  hipLaunchKernelGGL(k_scan3sm, dim3(1), dim3(256), 0, stream, y3t, bb3, pred, out);
}